// Round 4
// baseline (95.024 us; speedup 1.0000x reference)
//
#include <hip/hip_runtime.h>

// Table-batched embedding-bag, SUM pooling.
// weights: [T=8, E=250000, D=128] fp32
// indices: [T, B=4096, L=32] int32
// out:     [B, T*D] fp32, out[b, t*D + d] = sum_l weights[t, idx[t,b,l], d]
//
// R3 change vs R2: one FULL wave (64 lanes) per bag, lane owns float2 (8 B).
// A row load is still one fully-coalesced 512 B transaction (64 x 8 B), but
// blocks-per-table doubles (512 -> 1024), halving the number of tables whose
// working sets are concurrently live in the 256 MB L3 (~208 MB -> ~104 MB).
// Goal: duplicate row reads (~22% of gather traffic) become L3 hits.
// Output stores are non-temporal so the 16 MB write stream doesn't evict
// weight lines from L2/L3.

#define T_TABLES 8
#define E_ROWS   250000
#define D_DIM    128
#define B_BAGS   4096
#define L_POOL   32

__global__ __launch_bounds__(256) void embed_bag_pool_kernel(
    const float* __restrict__ weights,
    const int*   __restrict__ indices,
    float*       __restrict__ out)
{
    const int tid  = threadIdx.x;
    const int wave = tid >> 6;        // wave id within block: 0..3
    const int lane = tid & 63;        // lane within wave

    // bag id = t*B + b ; 4 bags per block; table-major dispatch order
    const unsigned bag = blockIdx.x * 4u + (unsigned)wave;
    const int t = (int)(bag >> 12);       // / 4096
    const int b = (int)(bag & 4095);      // % 4096

    const int* bag_idx = indices + ((size_t)t * B_BAGS + (size_t)b) * L_POOL;
    const float2* w_t  = (const float2*)(weights + (size_t)t * E_ROWS * D_DIM);
    // row stride in float2 units: D/2 = 64

    // Lanes 0..31 hold the bag's 32 indices (lanes 32..63 duplicate — same
    // cache line, free). Broadcast within the wave via shuffle.
    int my_idx = bag_idx[lane & 31];

    float2 acc = make_float2(0.f, 0.f);

#pragma unroll
    for (int l = 0; l < L_POOL; ++l) {
        int row = __shfl(my_idx, l, 64);
        float2 v = w_t[(size_t)row * (D_DIM / 2) + lane];
        acc.x += v.x;
        acc.y += v.y;
    }

    // out[b, t*D + 2*lane .. +1] — 512 B coalesced non-temporal store per wave.
    float2* outp = (float2*)(out + (size_t)b * (T_TABLES * D_DIM)
                                 + (size_t)t * D_DIM);
    union { float2 f; unsigned long long u; } cvt;
    cvt.f = acc;
    __builtin_nontemporal_store(cvt.u, (unsigned long long*)&outp[lane]);
}

extern "C" void kernel_launch(void* const* d_in, const int* in_sizes, int n_in,
                              void* d_out, int out_size, void* d_ws, size_t ws_size,
                              hipStream_t stream) {
    const float* weights = (const float*)d_in[0];
    const int*   indices = (const int*)d_in[1];
    float*       out     = (float*)d_out;

    const int total_bags = T_TABLES * B_BAGS;          // 32768
    const int blocks     = total_bags / 4;             // 8192 blocks of 256 thr

    embed_bag_pool_kernel<<<blocks, 256, 0, stream>>>(weights, indices, out);
}

// Round 5
// 86.593 us; speedup vs baseline: 1.0974x; 1.0974x over previous
//
#include <hip/hip_runtime.h>

// Table-batched embedding-bag, SUM pooling.
// weights: [T=8, E=250000, D=128] fp32
// indices: [T, B=4096, L=32] int32
// out:     [B, T*D] fp32, out[b, t*D + d] = sum_l weights[t, idx[t,b,l], d]
//
// R5: identical memory shape to R2 (half-wave of 32 lanes per bag, lane owns
// float4; one wave-load = 1024 B covering two bags' rows), but a PERSISTENT
// 1024-block grid sweeping bag-groups in table-major order (4 grid-stride
// iterations). At any instant ~2 tables (~104 MB unique rows) are active,
// fitting the 256 MB die-level Infinity Cache so duplicate row reads (~21%
// of gather traffic) convert from HBM fetches to L3 hits.

#define T_TABLES 8
#define E_ROWS   250000
#define D_DIM    128
#define B_BAGS   4096
#define L_POOL   32

#define GRID_BLOCKS 1024
#define BAGS_PER_BLOCK 8          // 256 threads = 8 half-waves
#define TOTAL_BAGS (T_TABLES * B_BAGS)   // 32768
#define SWEEPS (TOTAL_BAGS / (GRID_BLOCKS * BAGS_PER_BLOCK))  // 4

__global__ __launch_bounds__(256) void embed_bag_pool_kernel(
    const float* __restrict__ weights,
    const int*   __restrict__ indices,
    float*       __restrict__ out)
{
    const int tid    = threadIdx.x;
    const int group  = tid >> 5;      // half-wave id within block: 0..7
    const int lane32 = tid & 31;      // lane within half-wave

#pragma unroll
    for (int sweep = 0; sweep < SWEEPS; ++sweep) {
        // table-major bag ordering; blocks sweep tables roughly in lockstep
        const unsigned bag = (sweep * GRID_BLOCKS + blockIdx.x) * BAGS_PER_BLOCK
                           + (unsigned)group;
        const int t = (int)(bag >> 12);       // / 4096
        const int b = (int)(bag & 4095);      // % 4096

        const int* bag_idx = indices + ((size_t)t * B_BAGS + (size_t)b) * L_POOL;
        const float4* w_t  = (const float4*)(weights + (size_t)t * E_ROWS * D_DIM);

        // Each lane holds one of the bag's 32 indices; broadcast via shuffle.
        int my_idx = bag_idx[lane32];

        float4 acc = make_float4(0.f, 0.f, 0.f, 0.f);

#pragma unroll
        for (int l = 0; l < L_POOL; ++l) {
            int row = __shfl(my_idx, l, 32);
            float4 v = w_t[(size_t)row * (D_DIM / 4) + lane32];
            acc.x += v.x;
            acc.y += v.y;
            acc.z += v.z;
            acc.w += v.w;
        }

        // out[b, t*D + 4*lane32 .. +3] — 512 B coalesced store per half-wave.
        float4* outp = (float4*)(out + (size_t)b * (T_TABLES * D_DIM)
                                     + (size_t)t * D_DIM);
        outp[lane32] = acc;
    }
}

extern "C" void kernel_launch(void* const* d_in, const int* in_sizes, int n_in,
                              void* d_out, int out_size, void* d_ws, size_t ws_size,
                              hipStream_t stream) {
    const float* weights = (const float*)d_in[0];
    const int*   indices = (const int*)d_in[1];
    float*       out     = (float*)d_out;

    embed_bag_pool_kernel<<<GRID_BLOCKS, 256, 0, stream>>>(weights, indices, out);
}